// Round 7
// baseline (196.970 us; speedup 1.0000x reference)
//
#include <hip/hip_runtime.h>
#include <hip/hip_bf16.h>

// Problem constants (fixed by the reference)
#define I_CAPS 128
#define N_CAPS 5
#define D_CAPS 153
#define IN_DIM 768
#define NQ     256
#define CD     765      // N_CAPS * D_CAPS
#define HATLD  768      // padded leading dim of hat rows (cols 765..767 unused)
#define NPAIR  640      // I_CAPS * N_CAPS
#define EPSF   1e-8f

typedef __hip_bfloat16 bf16;

__device__ __forceinline__ float wred(float x) {
#pragma unroll
  for (int off = 32; off; off >>= 1) x += __shfl_down(x, off, 64);
  return x;
}

// Stable fast tanh: sign(x) * (1 - e^{-2|x|}) / (1 + e^{-2|x|})
__device__ __forceinline__ float tanh_fast(float x) {
  float t = __expf(-2.f * fabsf(x));
  float r = (1.f - t) / (1.f + t);
  return copysignf(r, x);
}

// ---------------------------------------------------------------------------
// Kernel 0: input-dtype classifier (resolved to f32 on this harness; kept for
// robustness). flag=1 -> bf16 inputs, flag=0 -> f32 inputs.
// ---------------------------------------------------------------------------
__global__ void classify_kernel(const unsigned* __restrict__ m_u32,
                                int* __restrict__ flag) {
  int lane = threadIdx.x & 63;
  unsigned u = m_u32[lane];
  int e = (u >> 7) & 0xFF;
  int hit = (e >= 118 && e <= 134) ? 1 : 0;
  unsigned long long mask = __ballot(hit);
  if (lane == 0) *flag = (__popcll(mask) >= 48) ? 1 : 0;
}

// ---------------------------------------------------------------------------
// Kernel 1: hat = [m;q] @ W + b. 16-row tiles: W column-slice read 24x
// (was 96x -> 4x less L2 traffic). grid (12, 24), block (64, 8).
// Each thread: 2 rows x 1 col, 4 accumulator chains.
// ---------------------------------------------------------------------------
template <bool ISB>
__device__ __forceinline__ float ld_in(const void* p, long idx) {
  if (ISB) return __bfloat162float(((const bf16*)p)[idx]);
  return ((const float*)p)[idx];
}

template <bool ISB>
__device__ void gemm_body(const void* m, const void* q, const void* W,
                          const void* b, float* hat) {
  __shared__ float As[16][IN_DIM];   // 48 KB
  const int tx = threadIdx.x, ty = threadIdx.y;
  const int t = ty * 64 + tx;        // 0..511
  const int row0 = blockIdx.y * 16;

  for (int e = t; e < 16 * IN_DIM; e += 512) {
    int rr = e / IN_DIM;
    int k = e - rr * IN_DIM;
    int row = row0 + rr;
    As[rr][k] = (row < I_CAPS)
                    ? ld_in<ISB>(m, (long)row * IN_DIM + k)
                    : ld_in<ISB>(q, (long)(row - I_CAPS) * IN_DIM + k);
  }
  __syncthreads();

  const int col = blockIdx.x * 64 + tx;
  const int colc = (col < CD) ? col : (CD - 1);   // clamp loads, guard store
  const int r0 = ty * 2, r1 = r0 + 1;

  float a0a = 0.f, a0b = 0.f, a1a = 0.f, a1b = 0.f;
  for (int k = 0; k < IN_DIM; k += 4) {
    const float4 A0 = *(const float4*)&As[r0][k];
    const float4 A1 = *(const float4*)&As[r1][k];
    float w0 = ld_in<ISB>(W, (long)(k + 0) * CD + colc);
    float w1 = ld_in<ISB>(W, (long)(k + 1) * CD + colc);
    float w2 = ld_in<ISB>(W, (long)(k + 2) * CD + colc);
    float w3 = ld_in<ISB>(W, (long)(k + 3) * CD + colc);
    a0a = fmaf(A0.x, w0, a0a);
    a0b = fmaf(A0.y, w1, a0b);
    a0a = fmaf(A0.z, w2, a0a);
    a0b = fmaf(A0.w, w3, a0b);
    a1a = fmaf(A1.x, w0, a1a);
    a1b = fmaf(A1.y, w1, a1b);
    a1a = fmaf(A1.z, w2, a1a);
    a1b = fmaf(A1.w, w3, a1b);
  }
  if (col < CD) {
    float bias = ld_in<ISB>(b, col);
    hat[(row0 + r0) * HATLD + col] = a0a + a0b + bias;
    hat[(row0 + r1) * HATLD + col] = a1a + a1b + bias;
  }
}

__global__ __launch_bounds__(512)
void gemm_kernel(const void* m, const void* q, const void* W, const void* b,
                 const int* __restrict__ flag, float* __restrict__ hat) {
  if (*flag)
    gemm_body<true>(m, q, W, b, hat);
  else
    gemm_body<false>(m, q, W, b, hat);
}

// ---------------------------------------------------------------------------
// Kernel 2: per-(i,c) stats of hat_m — one wave per pair. grid 160, block 256.
// ---------------------------------------------------------------------------
__global__ __launch_bounds__(256)
void stats_kernel(const float* __restrict__ hat,
                  float* __restrict__ mean_m, float* __restrict__ ssm) {
  const int wave = threadIdx.x >> 6, lane = threadIdx.x & 63;
  const int pair = blockIdx.x * 4 + wave;   // 640 pairs
  const int i = pair / N_CAPS, c = pair - i * N_CAPS;
  const float* hm = hat + i * HATLD + c * D_CAPS;
  float s = 0.f, s2 = 0.f;
  for (int d = lane; d < D_CAPS; d += 64) {
    float x = hm[d];
    s += x;
    s2 = fmaf(x, x, s2);
  }
  s = wred(s);
  s2 = wred(s2);
  if (lane == 0) {
    float mu = s * (1.f / D_CAPS);
    mean_m[pair] = mu;
    ssm[pair] = fmaxf(s2 - (float)D_CAPS * mu * mu, 0.f);
  }
}

// ---------------------------------------------------------------------------
// Kernel 3: routing — one block per query, 1024 threads (16 waves).
// One 8-lane group per memory capsule i (128 groups), 5 c-chains each.
// LDS tq/vv reads are same-address-per-sub -> broadcast (no bank conflicts).
// grid 256, block 1024.
// ---------------------------------------------------------------------------
__global__ __launch_bounds__(1024)
void routing_kernel(const float* __restrict__ hat,
                    const float* __restrict__ mean_m,
                    const float* __restrict__ ssm,
                    const int* __restrict__ flag,
                    void* __restrict__ out_v) {
  __shared__ float tq[CD], vv[CD];
  __shared__ float aa[NPAIR], pp[NPAIR], dsp[NPAIR];
  __shared__ float meanq[N_CAPS], ssq[N_CAPS], sscale[N_CAPS];

  const int tid = threadIdx.x;
  const int qi = blockIdx.x;
  const int w = tid >> 6, lane = tid & 63;
  const int g = tid >> 3, sub = tid & 7;   // 128 groups of 8 lanes; i = g
  const float* hq = hat + (I_CAPS + qi) * HATLD;
  const float* hm = hat + g * HATLD;       // this group's memory capsule row

  for (int cd = tid; cd < CD; cd += 1024) tq[cd] = hq[cd];
  for (int idx = tid; idx < NPAIR; idx += 1024) aa[idx] = 0.f;
  __syncthreads();

  // per-c stats of tq (waves 0..4)
  auto qstats = [&]() {
    if (w < N_CAPS) {
      const int c = w;
      float s = 0.f, s2 = 0.f;
      for (int d = lane; d < D_CAPS; d += 64) {
        float x = tq[c * D_CAPS + d];
        s += x;
        s2 = fmaf(x, x, s2);
      }
      s = wred(s);
      s2 = wred(s2);
      if (lane == 0) {
        float mu = s * (1.f / D_CAPS);
        meanq[c] = mu;
        ssq[c] = fmaxf(s2 - (float)D_CAPS * mu * mu, 0.f);
      }
    }
  };

  // 5-chain dot of hm row against LDS vector vec[c*153+d];
  // results summed across the 8-lane group (end up on all 8 lanes).
  #define DOT5(vec, A0, A1, A2, A3, A4)                                   \
    {                                                                     \
      _Pragma("unroll") for (int jj = 0; jj < 19; ++jj) {                 \
        int d = jj * 8 + sub;                                             \
        A0 = fmaf(hm[0 * D_CAPS + d], vec[0 * D_CAPS + d], A0);           \
        A1 = fmaf(hm[1 * D_CAPS + d], vec[1 * D_CAPS + d], A1);           \
        A2 = fmaf(hm[2 * D_CAPS + d], vec[2 * D_CAPS + d], A2);           \
        A3 = fmaf(hm[3 * D_CAPS + d], vec[3 * D_CAPS + d], A3);           \
        A4 = fmaf(hm[4 * D_CAPS + d], vec[4 * D_CAPS + d], A4);           \
      }                                                                   \
      if (sub == 0) {                                                     \
        A0 = fmaf(hm[0 * D_CAPS + 152], vec[0 * D_CAPS + 152], A0);       \
        A1 = fmaf(hm[1 * D_CAPS + 152], vec[1 * D_CAPS + 152], A1);       \
        A2 = fmaf(hm[2 * D_CAPS + 152], vec[2 * D_CAPS + 152], A2);       \
        A3 = fmaf(hm[3 * D_CAPS + 152], vec[3 * D_CAPS + 152], A3);       \
        A4 = fmaf(hm[4 * D_CAPS + 152], vec[4 * D_CAPS + 152], A4);       \
      }                                                                   \
      _Pragma("unroll") for (int off = 1; off < 8; off <<= 1) {           \
        A0 += __shfl_xor(A0, off, 64);                                    \
        A1 += __shfl_xor(A1, off, 64);                                    \
        A2 += __shfl_xor(A2, off, 64);                                    \
        A3 += __shfl_xor(A3, off, 64);                                    \
        A4 += __shfl_xor(A4, off, 64);                                    \
      }                                                                   \
    }

  auto sel5 = [&](float A0, float A1, float A2, float A3, float A4) {
    float r = A0;
    r = (sub == 1) ? A1 : r;
    r = (sub == 2) ? A2 : r;
    r = (sub == 3) ? A3 : r;
    r = (sub == 4) ? A4 : r;
    return r;
  };

  // p = tanh(pearson(hat_m_i, tq)) for all 5 c of row i=g
  auto compute_p = [&]() {
    float A0 = 0.f, A1 = 0.f, A2 = 0.f, A3 = 0.f, A4 = 0.f;
    DOT5(tq, A0, A1, A2, A3, A4);
    if (sub < N_CAPS) {
      float acc = sel5(A0, A1, A2, A3, A4);
      int pair = g * N_CAPS + sub;
      float num = acc - (float)D_CAPS * mean_m[pair] * meanq[sub];
      float den = sqrtf(ssm[pair]) * sqrtf(ssq[sub]) + EPSF;
      pp[pair] = tanh_fast(num / den);
    }
  };

  // a += p * (hat_m_i . v_c), v = sscale[c] * vv_raw
  auto mdot_aa = [&]() {
    float A0 = 0.f, A1 = 0.f, A2 = 0.f, A3 = 0.f, A4 = 0.f;
    DOT5(vv, A0, A1, A2, A3, A4);
    if (sub < N_CAPS) {
      float acc = sel5(A0, A1, A2, A3, A4);
      int pair = g * N_CAPS + sub;
      aa[pair] += pp[pair] * (sscale[sub] * acc);
    }
  };

  auto softmax_dsp = [&]() {
    if (tid < I_CAPS) {
      float av[N_CAPS], ev[N_CAPS];
      float mx = -1e30f;
#pragma unroll
      for (int c = 0; c < N_CAPS; ++c) {
        av[c] = aa[tid * N_CAPS + c];
        mx = fmaxf(mx, av[c]);
      }
      float s = 0.f;
#pragma unroll
      for (int c = 0; c < N_CAPS; ++c) {
        ev[c] = __expf(av[c] - mx);
        s += ev[c];
      }
      float inv = 1.f / s;
#pragma unroll
      for (int c = 0; c < N_CAPS; ++c)
        dsp[tid * N_CAPS + c] = ev[c] * inv + pp[tid * N_CAPS + c];
    }
  };

  // vv_raw[cd] = sum_i dsp[i,c] * hat_m[i,c,d]; 8 accumulator chains
  auto hat_v = [&]() {
    for (int cd = tid; cd < CD; cd += 1024) {
      int c = cd / D_CAPS;
      const float* col = hat + cd;
      float b0 = 0.f, b1 = 0.f, b2 = 0.f, b3 = 0.f;
      float b4 = 0.f, b5 = 0.f, b6 = 0.f, b7 = 0.f;
#pragma unroll 4
      for (int i = 0; i < I_CAPS; i += 8) {
        b0 = fmaf(dsp[(i + 0) * N_CAPS + c], col[(i + 0) * HATLD], b0);
        b1 = fmaf(dsp[(i + 1) * N_CAPS + c], col[(i + 1) * HATLD], b1);
        b2 = fmaf(dsp[(i + 2) * N_CAPS + c], col[(i + 2) * HATLD], b2);
        b3 = fmaf(dsp[(i + 3) * N_CAPS + c], col[(i + 3) * HATLD], b3);
        b4 = fmaf(dsp[(i + 4) * N_CAPS + c], col[(i + 4) * HATLD], b4);
        b5 = fmaf(dsp[(i + 5) * N_CAPS + c], col[(i + 5) * HATLD], b5);
        b6 = fmaf(dsp[(i + 6) * N_CAPS + c], col[(i + 6) * HATLD], b6);
        b7 = fmaf(dsp[(i + 7) * N_CAPS + c], col[(i + 7) * HATLD], b7);
      }
      vv[cd] = ((b0 + b1) + (b2 + b3)) + ((b4 + b5) + (b6 + b7));
    }
  };

  auto squash_scale = [&]() {
    if (w < N_CAPS) {
      const int c = w;
      float s2 = 0.f;
      for (int d = lane; d < D_CAPS; d += 64) {
        float x = vv[c * D_CAPS + d];
        s2 = fmaf(x, x, s2);
      }
      s2 = wred(s2);
      if (lane == 0) sscale[c] = (s2 / (1.f + s2)) * rsqrtf(s2 + EPSF);
    }
  };

  qstats();
  __syncthreads();
  compute_p();
  __syncthreads();

  for (int r = 0; r < 2; ++r) {
    softmax_dsp();
    __syncthreads();
    hat_v();
    __syncthreads();
    squash_scale();
    __syncthreads();
    mdot_aa();
    for (int cd = tid; cd < CD; cd += 1024)
      tq[cd] = 0.5f * (tq[cd] + vv[cd] * sscale[cd / D_CAPS]);
    __syncthreads();
    qstats();
    __syncthreads();
    compute_p();
    __syncthreads();
  }

  softmax_dsp();
  __syncthreads();
  hat_v();
  __syncthreads();
  squash_scale();
  __syncthreads();

  if (*flag == 0) {
    float* out = (float*)out_v;
    for (int cd = tid; cd < CD; cd += 1024)
      out[qi * CD + cd] = vv[cd] * sscale[cd / D_CAPS];
  } else {
    bf16* out = (bf16*)out_v;
    for (int cd = tid; cd < CD; cd += 1024)
      out[qi * CD + cd] = __float2bfloat16(vv[cd] * sscale[cd / D_CAPS]);
  }
  #undef DOT5
}

// ---------------------------------------------------------------------------
extern "C" void kernel_launch(void* const* d_in, const int* in_sizes, int n_in,
                              void* d_out, int out_size, void* d_ws, size_t ws_size,
                              hipStream_t stream) {
  // Bind inputs by element count (order-independent):
  // m=98304, q=196608, W=587520, b=765.
  const void *m = nullptr, *q = nullptr, *W = nullptr, *b = nullptr;
  for (int i = 0; i < n_in; ++i) {
    switch (in_sizes[i]) {
      case I_CAPS * IN_DIM: m = d_in[i]; break;
      case NQ * IN_DIM:     q = d_in[i]; break;
      case IN_DIM * CD:     W = d_in[i]; break;
      case CD:              b = d_in[i]; break;
      default: break;
    }
  }
  if (!m || !q || !W || !b) {
    m = d_in[0]; q = d_in[1]; W = d_in[2]; b = d_in[3];
  }

  int*   flag   = (int*)d_ws;
  float* mean_m = (float*)d_ws + 16;
  float* ssm    = mean_m + 640;
  float* hat    = ssm + 640;     // 384 * 768 f32

  classify_kernel<<<1, 64, 0, stream>>>((const unsigned*)m, flag);
  gemm_kernel<<<dim3(12, 24), dim3(64, 8), 0, stream>>>(m, q, W, b, flag, hat);
  stats_kernel<<<160, 256, 0, stream>>>(hat, mean_m, ssm);
  routing_kernel<<<NQ, 1024, 0, stream>>>(hat, mean_m, ssm, flag, d_out);
}

// Round 8
// 163.819 us; speedup vs baseline: 1.2024x; 1.2024x over previous
//
#include <hip/hip_runtime.h>
#include <hip/hip_bf16.h>

// Problem constants (fixed by the reference)
#define I_CAPS 128
#define N_CAPS 5
#define D_CAPS 153
#define D_PAD  160      // padded capsule dim for LDS vectors (zeros in 153..159)
#define IN_DIM 768
#define NQ     256
#define CD     765      // N_CAPS * D_CAPS
#define HATLD  768      // padded leading dim of hat rows (cols 765..767 unused)
#define NPAIR  640      // I_CAPS * N_CAPS
#define EPSF   1e-8f

typedef __hip_bfloat16 bf16;

__device__ __forceinline__ float wred(float x) {
#pragma unroll
  for (int off = 32; off; off >>= 1) x += __shfl_down(x, off, 64);
  return x;
}

// Stable fast tanh: sign(x) * (1 - e^{-2|x|}) / (1 + e^{-2|x|})
__device__ __forceinline__ float tanh_fast(float x) {
  float t = __expf(-2.f * fabsf(x));
  float r = (1.f - t) / (1.f + t);
  return copysignf(r, x);
}

// ---------------------------------------------------------------------------
// Kernel 0: input-dtype classifier (resolved to f32 on this harness; kept for
// robustness). flag=1 -> bf16 inputs, flag=0 -> f32 inputs.
// ---------------------------------------------------------------------------
__global__ void classify_kernel(const unsigned* __restrict__ m_u32,
                                int* __restrict__ flag) {
  int lane = threadIdx.x & 63;
  unsigned u = m_u32[lane];
  int e = (u >> 7) & 0xFF;
  int hit = (e >= 118 && e <= 134) ? 1 : 0;
  unsigned long long mask = __ballot(hit);
  if (lane == 0) *flag = (__popcll(mask) >= 48) ? 1 : 0;
}

// ---------------------------------------------------------------------------
// Kernel 1: hat = [m;q] @ W + b. 16-row tiles. grid (12, 24), block (64, 8).
// ---------------------------------------------------------------------------
template <bool ISB>
__device__ __forceinline__ float ld_in(const void* p, long idx) {
  if (ISB) return __bfloat162float(((const bf16*)p)[idx]);
  return ((const float*)p)[idx];
}

template <bool ISB>
__device__ void gemm_body(const void* m, const void* q, const void* W,
                          const void* b, float* hat) {
  __shared__ float As[16][IN_DIM];   // 48 KB
  const int tx = threadIdx.x, ty = threadIdx.y;
  const int t = ty * 64 + tx;        // 0..511
  const int row0 = blockIdx.y * 16;

  for (int e = t; e < 16 * IN_DIM; e += 512) {
    int rr = e / IN_DIM;
    int k = e - rr * IN_DIM;
    int row = row0 + rr;
    As[rr][k] = (row < I_CAPS)
                    ? ld_in<ISB>(m, (long)row * IN_DIM + k)
                    : ld_in<ISB>(q, (long)(row - I_CAPS) * IN_DIM + k);
  }
  __syncthreads();

  const int col = blockIdx.x * 64 + tx;
  const int colc = (col < CD) ? col : (CD - 1);   // clamp loads, guard store
  const int r0 = ty * 2, r1 = r0 + 1;

  float a0a = 0.f, a0b = 0.f, a1a = 0.f, a1b = 0.f;
  for (int k = 0; k < IN_DIM; k += 4) {
    const float4 A0 = *(const float4*)&As[r0][k];
    const float4 A1 = *(const float4*)&As[r1][k];
    float w0 = ld_in<ISB>(W, (long)(k + 0) * CD + colc);
    float w1 = ld_in<ISB>(W, (long)(k + 1) * CD + colc);
    float w2 = ld_in<ISB>(W, (long)(k + 2) * CD + colc);
    float w3 = ld_in<ISB>(W, (long)(k + 3) * CD + colc);
    a0a = fmaf(A0.x, w0, a0a);
    a0b = fmaf(A0.y, w1, a0b);
    a0a = fmaf(A0.z, w2, a0a);
    a0b = fmaf(A0.w, w3, a0b);
    a1a = fmaf(A1.x, w0, a1a);
    a1b = fmaf(A1.y, w1, a1b);
    a1a = fmaf(A1.z, w2, a1a);
    a1b = fmaf(A1.w, w3, a1b);
  }
  if (col < CD) {
    float bias = ld_in<ISB>(b, col);
    hat[(row0 + r0) * HATLD + col] = a0a + a0b + bias;
    hat[(row0 + r1) * HATLD + col] = a1a + a1b + bias;
  }
}

__global__ __launch_bounds__(512)
void gemm_kernel(const void* m, const void* q, const void* W, const void* b,
                 const int* __restrict__ flag, float* __restrict__ hat) {
  if (*flag)
    gemm_body<true>(m, q, W, b, hat);
  else
    gemm_body<false>(m, q, W, b, hat);
}

// ---------------------------------------------------------------------------
// Kernel 2: per-(i,c) stats of hat_m — one wave per pair. grid 160, block 256.
// ---------------------------------------------------------------------------
__global__ __launch_bounds__(256)
void stats_kernel(const float* __restrict__ hat,
                  float* __restrict__ mean_m, float* __restrict__ ssm) {
  const int wave = threadIdx.x >> 6, lane = threadIdx.x & 63;
  const int pair = blockIdx.x * 4 + wave;   // 640 pairs
  const int i = pair / N_CAPS, c = pair - i * N_CAPS;
  const float* hm = hat + i * HATLD + c * D_CAPS;
  float s = 0.f, s2 = 0.f;
  for (int d = lane; d < D_CAPS; d += 64) {
    float x = hm[d];
    s += x;
    s2 = fmaf(x, x, s2);
  }
  s = wred(s);
  s2 = wred(s2);
  if (lane == 0) {
    float mu = s * (1.f / D_CAPS);
    mean_m[pair] = mu;
    ssm[pair] = fmaxf(s2 - (float)D_CAPS * mu * mu, 0.f);
  }
}

// ---------------------------------------------------------------------------
// Kernel 3: routing — one block per query, 1024 threads (16 waves).
// One 8-lane group per memory capsule i (128 groups), 5 c-chains each.
// tq/vv padded to stride 160 (zeros in 153..159) -> uniform 20-iter DOT5.
// __launch_bounds__(1024,4): VGPR cap 128, no spills (round-7 lesson:
// full unroll at 64 VGPR spilled 73 MB of scratch).
// ---------------------------------------------------------------------------
__global__ __launch_bounds__(1024, 4)
void routing_kernel(const float* __restrict__ hat,
                    const float* __restrict__ mean_m,
                    const float* __restrict__ ssm,
                    const int* __restrict__ flag,
                    void* __restrict__ out_v) {
  __shared__ float tq[N_CAPS * D_PAD], vv[N_CAPS * D_PAD];
  __shared__ float aa[NPAIR], pp[NPAIR], dsp[NPAIR];
  __shared__ float meanq[N_CAPS], ssq[N_CAPS], sscale[N_CAPS];

  const int tid = threadIdx.x;
  const int qi = blockIdx.x;
  const int w = tid >> 6, lane = tid & 63;
  const int g = tid >> 3, sub = tid & 7;   // 128 groups of 8 lanes; i = g
  const float* hq = hat + (I_CAPS + qi) * HATLD;
  const float* hm = hat + g * HATLD;       // this group's memory capsule row

  // init: tq from hq (pad zeros), vv pads zero, a = 0
  for (int l = tid; l < N_CAPS * D_PAD; l += 1024) {
    int c = l / D_PAD, d = l - c * D_PAD;
    tq[l] = (d < D_CAPS) ? hq[c * D_CAPS + d] : 0.f;
    vv[l] = 0.f;
  }
  for (int idx = tid; idx < NPAIR; idx += 1024) aa[idx] = 0.f;
  __syncthreads();

  // per-c stats of tq (waves 0..4)
  auto qstats = [&]() {
    if (w < N_CAPS) {
      const int c = w;
      float s = 0.f, s2 = 0.f;
      for (int d = lane; d < D_CAPS; d += 64) {
        float x = tq[c * D_PAD + d];
        s += x;
        s2 = fmaf(x, x, s2);
      }
      s = wred(s);
      s2 = wred(s2);
      if (lane == 0) {
        float mu = s * (1.f / D_CAPS);
        meanq[c] = mu;
        ssq[c] = fmaxf(s2 - (float)D_CAPS * mu * mu, 0.f);
      }
    }
  };

  // 5-chain dot of hm row (global, stride-153 c-blocks) against padded LDS
  // vector vec[c*160+d]; 20 uniform iterations (pads contribute 0).
  // unroll 4: ~20 loads in flight, no spill.
  #define DOT5(vec, A0, A1, A2, A3, A4)                                   \
    {                                                                     \
      _Pragma("unroll 4") for (int jj = 0; jj < 20; ++jj) {               \
        int d = jj * 8 + sub;                                             \
        A0 = fmaf(hm[0 * D_CAPS + d], vec[0 * D_PAD + d], A0);            \
        A1 = fmaf(hm[1 * D_CAPS + d], vec[1 * D_PAD + d], A1);            \
        A2 = fmaf(hm[2 * D_CAPS + d], vec[2 * D_PAD + d], A2);            \
        A3 = fmaf(hm[3 * D_CAPS + d], vec[3 * D_PAD + d], A3);            \
        A4 = fmaf(hm[4 * D_CAPS + d], vec[4 * D_PAD + d], A4);            \
      }                                                                   \
      _Pragma("unroll") for (int off = 1; off < 8; off <<= 1) {           \
        A0 += __shfl_xor(A0, off, 64);                                    \
        A1 += __shfl_xor(A1, off, 64);                                    \
        A2 += __shfl_xor(A2, off, 64);                                    \
        A3 += __shfl_xor(A3, off, 64);                                    \
        A4 += __shfl_xor(A4, off, 64);                                    \
      }                                                                   \
    }

  auto sel5 = [&](float A0, float A1, float A2, float A3, float A4) {
    float r = A0;
    r = (sub == 1) ? A1 : r;
    r = (sub == 2) ? A2 : r;
    r = (sub == 3) ? A3 : r;
    r = (sub == 4) ? A4 : r;
    return r;
  };

  // p = tanh(pearson(hat_m_i, tq)) for all 5 c of row i=g
  auto compute_p = [&]() {
    float A0 = 0.f, A1 = 0.f, A2 = 0.f, A3 = 0.f, A4 = 0.f;
    DOT5(tq, A0, A1, A2, A3, A4);
    if (sub < N_CAPS) {
      float acc = sel5(A0, A1, A2, A3, A4);
      int pair = g * N_CAPS + sub;
      float num = acc - (float)D_CAPS * mean_m[pair] * meanq[sub];
      float den = sqrtf(ssm[pair]) * sqrtf(ssq[sub]) + EPSF;
      pp[pair] = tanh_fast(num / den);
    }
  };

  // a += p * (hat_m_i . v_c), v = sscale[c] * vv_raw
  auto mdot_aa = [&]() {
    float A0 = 0.f, A1 = 0.f, A2 = 0.f, A3 = 0.f, A4 = 0.f;
    DOT5(vv, A0, A1, A2, A3, A4);
    if (sub < N_CAPS) {
      float acc = sel5(A0, A1, A2, A3, A4);
      int pair = g * N_CAPS + sub;
      aa[pair] += pp[pair] * (sscale[sub] * acc);
    }
  };

  auto softmax_dsp = [&]() {
    if (tid < I_CAPS) {
      float av[N_CAPS], ev[N_CAPS];
      float mx = -1e30f;
#pragma unroll
      for (int c = 0; c < N_CAPS; ++c) {
        av[c] = aa[tid * N_CAPS + c];
        mx = fmaxf(mx, av[c]);
      }
      float s = 0.f;
#pragma unroll
      for (int c = 0; c < N_CAPS; ++c) {
        ev[c] = __expf(av[c] - mx);
        s += ev[c];
      }
      float inv = 1.f / s;
#pragma unroll
      for (int c = 0; c < N_CAPS; ++c)
        dsp[tid * N_CAPS + c] = ev[c] * inv + pp[tid * N_CAPS + c];
    }
  };

  // vv_raw[c*160+d] = sum_i dsp[i,c] * hat_m[i, c*153+d]; 8 chains
  auto hat_v = [&]() {
    for (int cd = tid; cd < CD; cd += 1024) {
      int c = cd / D_CAPS, d = cd - c * D_CAPS;
      const float* col = hat + cd;
      float b0 = 0.f, b1 = 0.f, b2 = 0.f, b3 = 0.f;
      float b4 = 0.f, b5 = 0.f, b6 = 0.f, b7 = 0.f;
#pragma unroll 4
      for (int i = 0; i < I_CAPS; i += 8) {
        b0 = fmaf(dsp[(i + 0) * N_CAPS + c], col[(i + 0) * HATLD], b0);
        b1 = fmaf(dsp[(i + 1) * N_CAPS + c], col[(i + 1) * HATLD], b1);
        b2 = fmaf(dsp[(i + 2) * N_CAPS + c], col[(i + 2) * HATLD], b2);
        b3 = fmaf(dsp[(i + 3) * N_CAPS + c], col[(i + 3) * HATLD], b3);
        b4 = fmaf(dsp[(i + 4) * N_CAPS + c], col[(i + 4) * HATLD], b4);
        b5 = fmaf(dsp[(i + 5) * N_CAPS + c], col[(i + 5) * HATLD], b5);
        b6 = fmaf(dsp[(i + 6) * N_CAPS + c], col[(i + 6) * HATLD], b6);
        b7 = fmaf(dsp[(i + 7) * N_CAPS + c], col[(i + 7) * HATLD], b7);
      }
      vv[c * D_PAD + d] = ((b0 + b1) + (b2 + b3)) + ((b4 + b5) + (b6 + b7));
    }
  };

  auto squash_scale = [&]() {
    if (w < N_CAPS) {
      const int c = w;
      float s2 = 0.f;
      for (int d = lane; d < D_CAPS; d += 64) {
        float x = vv[c * D_PAD + d];
        s2 = fmaf(x, x, s2);
      }
      s2 = wred(s2);
      if (lane == 0) sscale[c] = (s2 / (1.f + s2)) * rsqrtf(s2 + EPSF);
    }
  };

  qstats();
  __syncthreads();
  compute_p();
  __syncthreads();

  for (int r = 0; r < 2; ++r) {
    softmax_dsp();
    __syncthreads();
    hat_v();
    __syncthreads();
    squash_scale();
    __syncthreads();
    mdot_aa();
    for (int cd = tid; cd < CD; cd += 1024) {
      int c = cd / D_CAPS, d = cd - c * D_CAPS;
      int l = c * D_PAD + d;
      tq[l] = 0.5f * (tq[l] + vv[l] * sscale[c]);
    }
    __syncthreads();
    qstats();
    __syncthreads();
    compute_p();
    __syncthreads();
  }

  softmax_dsp();
  __syncthreads();
  hat_v();
  __syncthreads();
  squash_scale();
  __syncthreads();

  if (*flag == 0) {
    float* out = (float*)out_v;
    for (int cd = tid; cd < CD; cd += 1024) {
      int c = cd / D_CAPS, d = cd - c * D_CAPS;
      out[qi * CD + cd] = vv[c * D_PAD + d] * sscale[c];
    }
  } else {
    bf16* out = (bf16*)out_v;
    for (int cd = tid; cd < CD; cd += 1024) {
      int c = cd / D_CAPS, d = cd - c * D_CAPS;
      out[qi * CD + cd] = __float2bfloat16(vv[c * D_PAD + d] * sscale[c]);
    }
  }
  #undef DOT5
}

// ---------------------------------------------------------------------------
extern "C" void kernel_launch(void* const* d_in, const int* in_sizes, int n_in,
                              void* d_out, int out_size, void* d_ws, size_t ws_size,
                              hipStream_t stream) {
  // Bind inputs by element count (order-independent):
  // m=98304, q=196608, W=587520, b=765.
  const void *m = nullptr, *q = nullptr, *W = nullptr, *b = nullptr;
  for (int i = 0; i < n_in; ++i) {
    switch (in_sizes[i]) {
      case I_CAPS * IN_DIM: m = d_in[i]; break;
      case NQ * IN_DIM:     q = d_in[i]; break;
      case IN_DIM * CD:     W = d_in[i]; break;
      case CD:              b = d_in[i]; break;
      default: break;
    }
  }
  if (!m || !q || !W || !b) {
    m = d_in[0]; q = d_in[1]; W = d_in[2]; b = d_in[3];
  }

  int*   flag   = (int*)d_ws;
  float* mean_m = (float*)d_ws + 16;
  float* ssm    = mean_m + 640;
  float* hat    = ssm + 640;     // 384 * 768 f32

  classify_kernel<<<1, 64, 0, stream>>>((const unsigned*)m, flag);
  gemm_kernel<<<dim3(12, 24), dim3(64, 8), 0, stream>>>(m, q, W, b, flag, hat);
  stats_kernel<<<160, 256, 0, stream>>>(hat, mean_m, ssm);
  routing_kernel<<<NQ, 1024, 0, stream>>>(hat, mean_m, ssm, flag, d_out);
}

// Round 9
// 149.115 us; speedup vs baseline: 1.3209x; 1.0986x over previous
//
#include <hip/hip_runtime.h>
#include <hip/hip_bf16.h>

// Problem constants (fixed by the reference)
#define I_CAPS 128
#define N_CAPS 5
#define D_CAPS 153
#define D_PAD  160      // padded capsule dim (16B-aligned c-blocks, zeros in 153..159)
#define MLD    800      // hat_m leading dim = 5 * 160
#define IN_DIM 768
#define NQ     256
#define CD     765      // N_CAPS * D_CAPS
#define NPAIR  640      // I_CAPS * N_CAPS
#define EPSF   1e-8f

typedef __hip_bfloat16 bf16;

__device__ __forceinline__ float wred(float x) {
#pragma unroll
  for (int off = 32; off; off >>= 1) x += __shfl_down(x, off, 64);
  return x;
}

// Stable fast tanh: sign(x) * (1 - e^{-2|x|}) / (1 + e^{-2|x|})
__device__ __forceinline__ float tanh_fast(float x) {
  float t = __expf(-2.f * fabsf(x));
  float r = (1.f - t) / (1.f + t);
  return copysignf(r, x);
}

// ---------------------------------------------------------------------------
// Kernel 0: input-dtype classifier (resolves to f32 here; kept for robustness)
// ---------------------------------------------------------------------------
__global__ void classify_kernel(const unsigned* __restrict__ m_u32,
                                int* __restrict__ flag) {
  int lane = threadIdx.x & 63;
  unsigned u = m_u32[lane];
  int e = (u >> 7) & 0xFF;
  int hit = (e >= 118 && e <= 134) ? 1 : 0;
  unsigned long long mask = __ballot(hit);
  if (lane == 0) *flag = (__popcll(mask) >= 48) ? 1 : 0;
}

// ---------------------------------------------------------------------------
// Kernel 1: GEMM [m;q] @ W + b.
// Rows 0..127 -> hat_m (padded layout, c-stride 160); rows 128..383 -> hat_q
// (packed 765). grid (12, 24), block (64, 8).
// ---------------------------------------------------------------------------
template <bool ISB>
__device__ __forceinline__ float ld_in(const void* p, long idx) {
  if (ISB) return __bfloat162float(((const bf16*)p)[idx]);
  return ((const float*)p)[idx];
}

template <bool ISB>
__device__ void gemm_body(const void* m, const void* q, const void* W,
                          const void* b, float* hat_m, float* hat_q) {
  __shared__ float As[16][IN_DIM];   // 48 KB
  const int tx = threadIdx.x, ty = threadIdx.y;
  const int t = ty * 64 + tx;
  const int row0 = blockIdx.y * 16;

  for (int e = t; e < 16 * IN_DIM; e += 512) {
    int rr = e / IN_DIM;
    int k = e - rr * IN_DIM;
    int row = row0 + rr;
    As[rr][k] = (row < I_CAPS)
                    ? ld_in<ISB>(m, (long)row * IN_DIM + k)
                    : ld_in<ISB>(q, (long)(row - I_CAPS) * IN_DIM + k);
  }
  __syncthreads();

  const int col = blockIdx.x * 64 + tx;
  const int colc = (col < CD) ? col : (CD - 1);
  const int r0 = ty * 2, r1 = r0 + 1;

  float a0a = 0.f, a0b = 0.f, a1a = 0.f, a1b = 0.f;
  for (int k = 0; k < IN_DIM; k += 4) {
    const float4 A0 = *(const float4*)&As[r0][k];
    const float4 A1 = *(const float4*)&As[r1][k];
    float w0 = ld_in<ISB>(W, (long)(k + 0) * CD + colc);
    float w1 = ld_in<ISB>(W, (long)(k + 1) * CD + colc);
    float w2 = ld_in<ISB>(W, (long)(k + 2) * CD + colc);
    float w3 = ld_in<ISB>(W, (long)(k + 3) * CD + colc);
    a0a = fmaf(A0.x, w0, a0a);
    a0b = fmaf(A0.y, w1, a0b);
    a0a = fmaf(A0.z, w2, a0a);
    a0b = fmaf(A0.w, w3, a0b);
    a1a = fmaf(A1.x, w0, a1a);
    a1b = fmaf(A1.y, w1, a1b);
    a1a = fmaf(A1.z, w2, a1a);
    a1b = fmaf(A1.w, w3, a1b);
  }
  if (col < CD) {
    float bias = ld_in<ISB>(b, col);
    float v0 = a0a + a0b + bias;
    float v1 = a1a + a1b + bias;
    int c = col / D_CAPS, d = col - c * D_CAPS;
    int ra = row0 + r0, rb = row0 + r1;
    if (ra < I_CAPS) hat_m[ra * MLD + c * D_PAD + d] = v0;
    else             hat_q[(ra - I_CAPS) * CD + col] = v0;
    if (rb < I_CAPS) hat_m[rb * MLD + c * D_PAD + d] = v1;
    else             hat_q[(rb - I_CAPS) * CD + col] = v1;
  }
}

__global__ __launch_bounds__(512)
void gemm_kernel(const void* m, const void* q, const void* W, const void* b,
                 const int* __restrict__ flag,
                 float* __restrict__ hat_m, float* __restrict__ hat_q) {
  if (*flag)
    gemm_body<true>(m, q, W, b, hat_m, hat_q);
  else
    gemm_body<false>(m, q, W, b, hat_m, hat_q);
}

// ---------------------------------------------------------------------------
// Kernel 2: per-(i,c) stats of hat_m — one wave per pair. grid 160, block 256.
// ---------------------------------------------------------------------------
__global__ __launch_bounds__(256)
void stats_kernel(const float* __restrict__ hat_m,
                  float* __restrict__ mean_m, float* __restrict__ ssm) {
  const int wave = threadIdx.x >> 6, lane = threadIdx.x & 63;
  const int pair = blockIdx.x * 4 + wave;
  const int i = pair / N_CAPS, c = pair - i * N_CAPS;
  const float* hm = hat_m + i * MLD + c * D_PAD;
  float s = 0.f, s2 = 0.f;
  for (int d = lane; d < D_CAPS; d += 64) {
    float x = hm[d];
    s += x;
    s2 = fmaf(x, x, s2);
  }
  s = wred(s);
  s2 = wred(s2);
  if (lane == 0) {
    float mu = s * (1.f / D_CAPS);
    mean_m[pair] = mu;
    ssm[pair] = fmaxf(s2 - (float)D_CAPS * mu * mu, 0.f);
  }
}

// ---------------------------------------------------------------------------
// Kernel 3: routing — one block per query, 1024 threads.
// Incremental pearson: S[i,c]=hm.tq kept in LDS; since tq'=(tq+v)/2 and
// hm.v is computed by the mdot phase anyway, rounds 2-3 need NO hat_m pass
// for p. DOT5 uses float4/b128 (hat_m c-blocks 16B aligned, stride 160).
// ---------------------------------------------------------------------------
__global__ __launch_bounds__(1024, 4)
void routing_kernel(const float* __restrict__ hat_m,
                    const float* __restrict__ hat_q,
                    const float* __restrict__ mean_m,
                    const float* __restrict__ ssm,
                    const int* __restrict__ flag,
                    void* __restrict__ out_v) {
  __shared__ float tq[N_CAPS * D_PAD], vv[N_CAPS * D_PAD];
  __shared__ float aa[NPAIR], pp[NPAIR], dsp[NPAIR], sdot[NPAIR];
  __shared__ float smm[NPAIR], sss[NPAIR];
  __shared__ float meanq[N_CAPS], ssq[N_CAPS], sscale[N_CAPS];

  const int tid = threadIdx.x;
  const int qi = blockIdx.x;
  const int w = tid >> 6, lane = tid & 63;
  const int g = tid >> 3, sub = tid & 7;   // 128 groups of 8 lanes; i = g
  const float* hq = hat_q + qi * CD;
  const float* hm = hat_m + g * MLD;       // this group's memory capsule row

  // init: tq from hq (pads zero), vv pads zero, a=0, cache stats in LDS
  for (int l = tid; l < N_CAPS * D_PAD; l += 1024) {
    int c = l / D_PAD, d = l - c * D_PAD;
    tq[l] = (d < D_CAPS) ? hq[c * D_CAPS + d] : 0.f;
    vv[l] = 0.f;
  }
  if (tid < NPAIR) {
    aa[tid] = 0.f;
    smm[tid] = mean_m[tid];
    sss[tid] = ssm[tid];
  }
  __syncthreads();

  auto qstats = [&]() {
    if (w < N_CAPS) {
      const int c = w;
      float s = 0.f, s2 = 0.f;
      for (int d = lane; d < D_CAPS; d += 64) {
        float x = tq[c * D_PAD + d];
        s += x;
        s2 = fmaf(x, x, s2);
      }
      s = wred(s);
      s2 = wred(s2);
      if (lane == 0) {
        float mu = s * (1.f / D_CAPS);
        meanq[c] = mu;
        ssq[c] = fmaxf(s2 - (float)D_CAPS * mu * mu, 0.f);
      }
    }
  };

  // 5-chain float4 dot of hm row against padded LDS vector (20 floats/lane/c)
  #define DOT5(vec, A0, A1, A2, A3, A4)                                   \
    {                                                                     \
      _Pragma("unroll 2") for (int jj = 0; jj < 5; ++jj) {                \
        int d = jj * 32 + sub * 4;                                        \
        float4 h0 = *(const float4*)(hm + 0 * D_PAD + d);                 \
        float4 h1 = *(const float4*)(hm + 1 * D_PAD + d);                 \
        float4 h2 = *(const float4*)(hm + 2 * D_PAD + d);                 \
        float4 h3 = *(const float4*)(hm + 3 * D_PAD + d);                 \
        float4 h4 = *(const float4*)(hm + 4 * D_PAD + d);                 \
        float4 t0 = *(const float4*)(vec + 0 * D_PAD + d);                \
        float4 t1 = *(const float4*)(vec + 1 * D_PAD + d);                \
        float4 t2 = *(const float4*)(vec + 2 * D_PAD + d);                \
        float4 t3 = *(const float4*)(vec + 3 * D_PAD + d);                \
        float4 t4 = *(const float4*)(vec + 4 * D_PAD + d);                \
        A0 = fmaf(h0.x, t0.x, A0); A0 = fmaf(h0.y, t0.y, A0);             \
        A0 = fmaf(h0.z, t0.z, A0); A0 = fmaf(h0.w, t0.w, A0);             \
        A1 = fmaf(h1.x, t1.x, A1); A1 = fmaf(h1.y, t1.y, A1);             \
        A1 = fmaf(h1.z, t1.z, A1); A1 = fmaf(h1.w, t1.w, A1);             \
        A2 = fmaf(h2.x, t2.x, A2); A2 = fmaf(h2.y, t2.y, A2);             \
        A2 = fmaf(h2.z, t2.z, A2); A2 = fmaf(h2.w, t2.w, A2);             \
        A3 = fmaf(h3.x, t3.x, A3); A3 = fmaf(h3.y, t3.y, A3);             \
        A3 = fmaf(h3.z, t3.z, A3); A3 = fmaf(h3.w, t3.w, A3);             \
        A4 = fmaf(h4.x, t4.x, A4); A4 = fmaf(h4.y, t4.y, A4);             \
        A4 = fmaf(h4.z, t4.z, A4); A4 = fmaf(h4.w, t4.w, A4);             \
      }                                                                   \
      _Pragma("unroll") for (int off = 1; off < 8; off <<= 1) {           \
        A0 += __shfl_xor(A0, off, 64);                                    \
        A1 += __shfl_xor(A1, off, 64);                                    \
        A2 += __shfl_xor(A2, off, 64);                                    \
        A3 += __shfl_xor(A3, off, 64);                                    \
        A4 += __shfl_xor(A4, off, 64);                                    \
      }                                                                   \
    }

  auto sel5 = [&](float A0, float A1, float A2, float A3, float A4) {
    float r = A0;
    r = (sub == 1) ? A1 : r;
    r = (sub == 2) ? A2 : r;
    r = (sub == 3) ? A3 : r;
    r = (sub == 4) ? A4 : r;
    return r;
  };

  // initial: S = hm.tq (the only tq-DOT5 in the kernel) + p from S
  auto init_S_p = [&]() {
    float A0 = 0.f, A1 = 0.f, A2 = 0.f, A3 = 0.f, A4 = 0.f;
    DOT5(tq, A0, A1, A2, A3, A4);
    if (sub < N_CAPS) {
      float acc = sel5(A0, A1, A2, A3, A4);
      int pair = g * N_CAPS + sub;
      sdot[pair] = acc;
      float num = acc - (float)D_CAPS * smm[pair] * meanq[sub];
      float den = sqrtf(sss[pair]) * sqrtf(ssq[sub]) + EPSF;
      pp[pair] = tanh_fast(num / den);
    }
  };

  // mdot: raw = hm.vv_raw; a += p*sscale*raw; S = 0.5*(S + sscale*raw)
  auto mdot_aa = [&]() {
    float A0 = 0.f, A1 = 0.f, A2 = 0.f, A3 = 0.f, A4 = 0.f;
    DOT5(vv, A0, A1, A2, A3, A4);
    if (sub < N_CAPS) {
      float acc = sel5(A0, A1, A2, A3, A4);
      int pair = g * N_CAPS + sub;
      float mdv = sscale[sub] * acc;
      aa[pair] += pp[pair] * mdv;
      sdot[pair] = 0.5f * (sdot[pair] + mdv);
    }
  };

  // p from stored S (no hat_m pass)
  auto p_from_S = [&]() {
    if (tid < NPAIR) {
      int c = tid - (tid / N_CAPS) * N_CAPS;
      float num = sdot[tid] - (float)D_CAPS * smm[tid] * meanq[c];
      float den = sqrtf(sss[tid]) * sqrtf(ssq[c]) + EPSF;
      pp[tid] = tanh_fast(num / den);
    }
  };

  auto softmax_dsp = [&]() {
    if (tid < I_CAPS) {
      float av[N_CAPS], ev[N_CAPS];
      float mx = -1e30f;
#pragma unroll
      for (int c = 0; c < N_CAPS; ++c) {
        av[c] = aa[tid * N_CAPS + c];
        mx = fmaxf(mx, av[c]);
      }
      float s = 0.f;
#pragma unroll
      for (int c = 0; c < N_CAPS; ++c) {
        ev[c] = __expf(av[c] - mx);
        s += ev[c];
      }
      float inv = 1.f / s;
#pragma unroll
      for (int c = 0; c < N_CAPS; ++c)
        dsp[tid * N_CAPS + c] = ev[c] * inv + pp[tid * N_CAPS + c];
    }
  };

  // vv_raw[c*160+d] = sum_i dsp[i,c] * hat_m[i][c*160+d]; 8 chains
  auto hat_v = [&]() {
    for (int cd = tid; cd < CD; cd += 1024) {
      int c = cd / D_CAPS, d = cd - c * D_CAPS;
      const float* col = hat_m + c * D_PAD + d;
      float b0 = 0.f, b1 = 0.f, b2 = 0.f, b3 = 0.f;
      float b4 = 0.f, b5 = 0.f, b6 = 0.f, b7 = 0.f;
#pragma unroll 4
      for (int i = 0; i < I_CAPS; i += 8) {
        b0 = fmaf(dsp[(i + 0) * N_CAPS + c], col[(i + 0) * MLD], b0);
        b1 = fmaf(dsp[(i + 1) * N_CAPS + c], col[(i + 1) * MLD], b1);
        b2 = fmaf(dsp[(i + 2) * N_CAPS + c], col[(i + 2) * MLD], b2);
        b3 = fmaf(dsp[(i + 3) * N_CAPS + c], col[(i + 3) * MLD], b3);
        b4 = fmaf(dsp[(i + 4) * N_CAPS + c], col[(i + 4) * MLD], b4);
        b5 = fmaf(dsp[(i + 5) * N_CAPS + c], col[(i + 5) * MLD], b5);
        b6 = fmaf(dsp[(i + 6) * N_CAPS + c], col[(i + 6) * MLD], b6);
        b7 = fmaf(dsp[(i + 7) * N_CAPS + c], col[(i + 7) * MLD], b7);
      }
      vv[c * D_PAD + d] = ((b0 + b1) + (b2 + b3)) + ((b4 + b5) + (b6 + b7));
    }
  };

  auto squash_scale = [&]() {
    if (w < N_CAPS) {
      const int c = w;
      float s2 = 0.f;
      for (int d = lane; d < D_CAPS; d += 64) {
        float x = vv[c * D_PAD + d];
        s2 = fmaf(x, x, s2);
      }
      s2 = wred(s2);
      if (lane == 0) sscale[c] = (s2 / (1.f + s2)) * rsqrtf(s2 + EPSF);
    }
  };

  qstats();
  __syncthreads();
  init_S_p();
  __syncthreads();

  for (int r = 0; r < 2; ++r) {
    softmax_dsp();
    __syncthreads();
    hat_v();
    __syncthreads();
    squash_scale();
    __syncthreads();
    mdot_aa();
    for (int cd = tid; cd < CD; cd += 1024) {
      int c = cd / D_CAPS, d = cd - c * D_CAPS;
      int l = c * D_PAD + d;
      tq[l] = 0.5f * (tq[l] + vv[l] * sscale[c]);
    }
    __syncthreads();
    qstats();
    __syncthreads();
    p_from_S();
    __syncthreads();
  }

  softmax_dsp();
  __syncthreads();
  hat_v();
  __syncthreads();
  squash_scale();
  __syncthreads();

  if (*flag == 0) {
    float* out = (float*)out_v;
    for (int cd = tid; cd < CD; cd += 1024) {
      int c = cd / D_CAPS, d = cd - c * D_CAPS;
      out[qi * CD + cd] = vv[c * D_PAD + d] * sscale[c];
    }
  } else {
    bf16* out = (bf16*)out_v;
    for (int cd = tid; cd < CD; cd += 1024) {
      int c = cd / D_CAPS, d = cd - c * D_CAPS;
      out[qi * CD + cd] = __float2bfloat16(vv[c * D_PAD + d] * sscale[c]);
    }
  }
  #undef DOT5
}

// ---------------------------------------------------------------------------
extern "C" void kernel_launch(void* const* d_in, const int* in_sizes, int n_in,
                              void* d_out, int out_size, void* d_ws, size_t ws_size,
                              hipStream_t stream) {
  // Bind inputs by element count (order-independent):
  // m=98304, q=196608, W=587520, b=765.
  const void *m = nullptr, *q = nullptr, *W = nullptr, *b = nullptr;
  for (int i = 0; i < n_in; ++i) {
    switch (in_sizes[i]) {
      case I_CAPS * IN_DIM: m = d_in[i]; break;
      case NQ * IN_DIM:     q = d_in[i]; break;
      case IN_DIM * CD:     W = d_in[i]; break;
      case CD:              b = d_in[i]; break;
      default: break;
    }
  }
  if (!m || !q || !W || !b) {
    m = d_in[0]; q = d_in[1]; W = d_in[2]; b = d_in[3];
  }

  int*   flag   = (int*)d_ws;
  float* mean_m = (float*)d_ws + 16;                 // 640
  float* ssm    = mean_m + 640;                      // 640
  float* hat_m  = ssm + 640;                         // 128 * 800 f32 (padded)
  float* hat_q  = hat_m + I_CAPS * MLD;              // 256 * 765 f32 (packed)

  classify_kernel<<<1, 64, 0, stream>>>((const unsigned*)m, flag);
  // zero hat_m pads (cols c*160+153..159) before GEMM fills the rest
  hipMemsetAsync(hat_m, 0, (size_t)I_CAPS * MLD * sizeof(float), stream);
  gemm_kernel<<<dim3(12, 24), dim3(64, 8), 0, stream>>>(m, q, W, b, flag,
                                                        hat_m, hat_q);
  stats_kernel<<<160, 256, 0, stream>>>(hat_m, mean_m, ssm);
  routing_kernel<<<NQ, 1024, 0, stream>>>(hat_m, hat_q, mean_m, ssm, flag,
                                          d_out);
}

// Round 10
// 127.947 us; speedup vs baseline: 1.5395x; 1.1654x over previous
//
#include <hip/hip_runtime.h>
#include <hip/hip_bf16.h>

// Problem constants (fixed by the reference)
#define I_CAPS 128
#define N_CAPS 5
#define D_CAPS 153
#define D_PAD  160      // padded capsule dim (16B-aligned c-blocks, zeros in 153..159)
#define MLD    800      // hat_m leading dim = 5 * 160
#define IN_DIM 768
#define NQ     256
#define CD     765      // N_CAPS * D_CAPS
#define NPAIR  640      // I_CAPS * N_CAPS
#define EPSF   1e-8f
#define KHALF  384      // IN_DIM / 2 (split-K)

typedef __hip_bfloat16 bf16;

__device__ __forceinline__ float wred(float x) {
#pragma unroll
  for (int off = 32; off; off >>= 1) x += __shfl_down(x, off, 64);
  return x;
}

// Stable fast tanh: sign(x) * (1 - e^{-2|x|}) / (1 + e^{-2|x|})
__device__ __forceinline__ float tanh_fast(float x) {
  float t = __expf(-2.f * fabsf(x));
  float r = (1.f - t) / (1.f + t);
  return copysignf(r, x);
}

// ---------------------------------------------------------------------------
// Kernel 0: input-dtype classifier (resolves to f32 here; kept for robustness)
// ---------------------------------------------------------------------------
__global__ void classify_kernel(const unsigned* __restrict__ m_u32,
                                int* __restrict__ flag) {
  int lane = threadIdx.x & 63;
  unsigned u = m_u32[lane];
  int e = (u >> 7) & 0xFF;
  int hit = (e >= 118 && e <= 134) ? 1 : 0;
  unsigned long long mask = __ballot(hit);
  if (lane == 0) *flag = (__popcll(mask) >= 48) ? 1 : 0;
}

// ---------------------------------------------------------------------------
// Kernel 1: GEMM v4 — split-K x2, 8-row x 64-col tiles, atomicAdd combine.
// grid (12, 48, 2), block (64, 4). LDS only 12 KB -> high occupancy
// (round-9 lesson: 48/96 KB LDS capped us at 1 block/CU, 14% occupancy).
// hat buffers pre-zeroed; kb==0 adds bias.
// ---------------------------------------------------------------------------
template <bool ISB>
__device__ __forceinline__ float ld_in(const void* p, long idx) {
  if (ISB) return __bfloat162float(((const bf16*)p)[idx]);
  return ((const float*)p)[idx];
}

template <bool ISB>
__device__ void gemm_body(const void* m, const void* q, const void* W,
                          const void* b, float* hat_m, float* hat_q) {
  __shared__ float As[8][KHALF];   // 12 KB
  const int tx = threadIdx.x, ty = threadIdx.y;
  const int t = ty * 64 + tx;      // 0..255
  const int row0 = blockIdx.y * 8;
  const int k0 = blockIdx.z * KHALF;

  // stage 8 rows x 384 k (this block's k-half) into LDS
  if (ISB) {
    for (int e = t; e < 8 * KHALF; e += 256) {
      int rr = e / KHALF, kk = e - rr * KHALF;
      int row = row0 + rr;
      As[rr][kk] = (row < I_CAPS)
                       ? ld_in<true>(m, (long)row * IN_DIM + k0 + kk)
                       : ld_in<true>(q, (long)(row - I_CAPS) * IN_DIM + k0 + kk);
    }
  } else {
    // float4 staging: 8*384/4 = 768 vec4 elements
    for (int e = t; e < 8 * (KHALF / 4); e += 256) {
      int rr = e / (KHALF / 4), k4 = e - rr * (KHALF / 4);
      int row = row0 + rr;
      const float* src = (row < I_CAPS)
                             ? (const float*)m + (long)row * IN_DIM
                             : (const float*)q + (long)(row - I_CAPS) * IN_DIM;
      *(float4*)&As[rr][k4 * 4] = *(const float4*)(src + k0 + k4 * 4);
    }
  }
  __syncthreads();

  const int col = blockIdx.x * 64 + tx;
  const int colc = (col < CD) ? col : (CD - 1);
  const int r0 = ty * 2, r1 = r0 + 1;

  float a0a = 0.f, a0b = 0.f, a1a = 0.f, a1b = 0.f;
#pragma unroll 2
  for (int k = 0; k < KHALF; k += 8) {
    const float4 A0a = *(const float4*)&As[r0][k];
    const float4 A0b = *(const float4*)&As[r0][k + 4];
    const float4 A1a = *(const float4*)&As[r1][k];
    const float4 A1b = *(const float4*)&As[r1][k + 4];
    float w0 = ld_in<ISB>(W, (long)(k0 + k + 0) * CD + colc);
    float w1 = ld_in<ISB>(W, (long)(k0 + k + 1) * CD + colc);
    float w2 = ld_in<ISB>(W, (long)(k0 + k + 2) * CD + colc);
    float w3 = ld_in<ISB>(W, (long)(k0 + k + 3) * CD + colc);
    float w4 = ld_in<ISB>(W, (long)(k0 + k + 4) * CD + colc);
    float w5 = ld_in<ISB>(W, (long)(k0 + k + 5) * CD + colc);
    float w6 = ld_in<ISB>(W, (long)(k0 + k + 6) * CD + colc);
    float w7 = ld_in<ISB>(W, (long)(k0 + k + 7) * CD + colc);
    a0a = fmaf(A0a.x, w0, a0a); a0b = fmaf(A0a.y, w1, a0b);
    a0a = fmaf(A0a.z, w2, a0a); a0b = fmaf(A0a.w, w3, a0b);
    a0a = fmaf(A0b.x, w4, a0a); a0b = fmaf(A0b.y, w5, a0b);
    a0a = fmaf(A0b.z, w6, a0a); a0b = fmaf(A0b.w, w7, a0b);
    a1a = fmaf(A1a.x, w0, a1a); a1b = fmaf(A1a.y, w1, a1b);
    a1a = fmaf(A1a.z, w2, a1a); a1b = fmaf(A1a.w, w3, a1b);
    a1a = fmaf(A1b.x, w4, a1a); a1b = fmaf(A1b.y, w5, a1b);
    a1a = fmaf(A1b.z, w6, a1a); a1b = fmaf(A1b.w, w7, a1b);
  }

  if (col < CD) {
    float p0 = a0a + a0b;
    float p1 = a1a + a1b;
    if (blockIdx.z == 0) {
      float bias = ld_in<ISB>(b, col);
      p0 += bias;
      p1 += bias;
    }
    int c = col / D_CAPS, d = col - c * D_CAPS;
    int ra = row0 + r0, rb = row0 + r1;
    float* d0 = (ra < I_CAPS) ? &hat_m[ra * MLD + c * D_PAD + d]
                              : &hat_q[(ra - I_CAPS) * CD + col];
    float* d1 = (rb < I_CAPS) ? &hat_m[rb * MLD + c * D_PAD + d]
                              : &hat_q[(rb - I_CAPS) * CD + col];
    atomicAdd(d0, p0);
    atomicAdd(d1, p1);
  }
}

__global__ __launch_bounds__(256, 4)
void gemm_kernel(const void* m, const void* q, const void* W, const void* b,
                 const int* __restrict__ flag,
                 float* __restrict__ hat_m, float* __restrict__ hat_q) {
  if (*flag)
    gemm_body<true>(m, q, W, b, hat_m, hat_q);
  else
    gemm_body<false>(m, q, W, b, hat_m, hat_q);
}

// ---------------------------------------------------------------------------
// Kernel 2: per-(i,c) stats of hat_m — one wave per pair. grid 160, block 256.
// ---------------------------------------------------------------------------
__global__ __launch_bounds__(256)
void stats_kernel(const float* __restrict__ hat_m,
                  float* __restrict__ mean_m, float* __restrict__ ssm) {
  const int wave = threadIdx.x >> 6, lane = threadIdx.x & 63;
  const int pair = blockIdx.x * 4 + wave;
  const int i = pair / N_CAPS, c = pair - i * N_CAPS;
  const float* hm = hat_m + i * MLD + c * D_PAD;
  float s = 0.f, s2 = 0.f;
  for (int d = lane; d < D_CAPS; d += 64) {
    float x = hm[d];
    s += x;
    s2 = fmaf(x, x, s2);
  }
  s = wred(s);
  s2 = wred(s2);
  if (lane == 0) {
    float mu = s * (1.f / D_CAPS);
    mean_m[pair] = mu;
    ssm[pair] = fmaxf(s2 - (float)D_CAPS * mu * mu, 0.f);
  }
}

// ---------------------------------------------------------------------------
// Kernel 3: routing — one block per query, 1024 threads.
// Incremental pearson via S[i,c] state; float4/b128 DOT5 (hat_m stride 160).
// ---------------------------------------------------------------------------
__global__ __launch_bounds__(1024, 4)
void routing_kernel(const float* __restrict__ hat_m,
                    const float* __restrict__ hat_q,
                    const float* __restrict__ mean_m,
                    const float* __restrict__ ssm,
                    const int* __restrict__ flag,
                    void* __restrict__ out_v) {
  __shared__ float tq[N_CAPS * D_PAD], vv[N_CAPS * D_PAD];
  __shared__ float aa[NPAIR], pp[NPAIR], dsp[NPAIR], sdot[NPAIR];
  __shared__ float smm[NPAIR], sss[NPAIR];
  __shared__ float meanq[N_CAPS], ssq[N_CAPS], sscale[N_CAPS];

  const int tid = threadIdx.x;
  const int qi = blockIdx.x;
  const int w = tid >> 6, lane = tid & 63;
  const int g = tid >> 3, sub = tid & 7;   // 128 groups of 8 lanes; i = g
  const float* hq = hat_q + qi * CD;
  const float* hm = hat_m + g * MLD;       // this group's memory capsule row

  for (int l = tid; l < N_CAPS * D_PAD; l += 1024) {
    int c = l / D_PAD, d = l - c * D_PAD;
    tq[l] = (d < D_CAPS) ? hq[c * D_CAPS + d] : 0.f;
    vv[l] = 0.f;
  }
  if (tid < NPAIR) {
    aa[tid] = 0.f;
    smm[tid] = mean_m[tid];
    sss[tid] = ssm[tid];
  }
  __syncthreads();

  auto qstats = [&]() {
    if (w < N_CAPS) {
      const int c = w;
      float s = 0.f, s2 = 0.f;
      for (int d = lane; d < D_CAPS; d += 64) {
        float x = tq[c * D_PAD + d];
        s += x;
        s2 = fmaf(x, x, s2);
      }
      s = wred(s);
      s2 = wred(s2);
      if (lane == 0) {
        float mu = s * (1.f / D_CAPS);
        meanq[c] = mu;
        ssq[c] = fmaxf(s2 - (float)D_CAPS * mu * mu, 0.f);
      }
    }
  };

  #define DOT5(vec, A0, A1, A2, A3, A4)                                   \
    {                                                                     \
      _Pragma("unroll 2") for (int jj = 0; jj < 5; ++jj) {                \
        int d = jj * 32 + sub * 4;                                        \
        float4 h0 = *(const float4*)(hm + 0 * D_PAD + d);                 \
        float4 h1 = *(const float4*)(hm + 1 * D_PAD + d);                 \
        float4 h2 = *(const float4*)(hm + 2 * D_PAD + d);                 \
        float4 h3 = *(const float4*)(hm + 3 * D_PAD + d);                 \
        float4 h4 = *(const float4*)(hm + 4 * D_PAD + d);                 \
        float4 t0 = *(const float4*)(vec + 0 * D_PAD + d);                \
        float4 t1 = *(const float4*)(vec + 1 * D_PAD + d);                \
        float4 t2 = *(const float4*)(vec + 2 * D_PAD + d);                \
        float4 t3 = *(const float4*)(vec + 3 * D_PAD + d);                \
        float4 t4 = *(const float4*)(vec + 4 * D_PAD + d);                \
        A0 = fmaf(h0.x, t0.x, A0); A0 = fmaf(h0.y, t0.y, A0);             \
        A0 = fmaf(h0.z, t0.z, A0); A0 = fmaf(h0.w, t0.w, A0);             \
        A1 = fmaf(h1.x, t1.x, A1); A1 = fmaf(h1.y, t1.y, A1);             \
        A1 = fmaf(h1.z, t1.z, A1); A1 = fmaf(h1.w, t1.w, A1);             \
        A2 = fmaf(h2.x, t2.x, A2); A2 = fmaf(h2.y, t2.y, A2);             \
        A2 = fmaf(h2.z, t2.z, A2); A2 = fmaf(h2.w, t2.w, A2);             \
        A3 = fmaf(h3.x, t3.x, A3); A3 = fmaf(h3.y, t3.y, A3);             \
        A3 = fmaf(h3.z, t3.z, A3); A3 = fmaf(h3.w, t3.w, A3);             \
        A4 = fmaf(h4.x, t4.x, A4); A4 = fmaf(h4.y, t4.y, A4);             \
        A4 = fmaf(h4.z, t4.z, A4); A4 = fmaf(h4.w, t4.w, A4);             \
      }                                                                   \
      _Pragma("unroll") for (int off = 1; off < 8; off <<= 1) {           \
        A0 += __shfl_xor(A0, off, 64);                                    \
        A1 += __shfl_xor(A1, off, 64);                                    \
        A2 += __shfl_xor(A2, off, 64);                                    \
        A3 += __shfl_xor(A3, off, 64);                                    \
        A4 += __shfl_xor(A4, off, 64);                                    \
      }                                                                   \
    }

  auto sel5 = [&](float A0, float A1, float A2, float A3, float A4) {
    float r = A0;
    r = (sub == 1) ? A1 : r;
    r = (sub == 2) ? A2 : r;
    r = (sub == 3) ? A3 : r;
    r = (sub == 4) ? A4 : r;
    return r;
  };

  auto init_S_p = [&]() {
    float A0 = 0.f, A1 = 0.f, A2 = 0.f, A3 = 0.f, A4 = 0.f;
    DOT5(tq, A0, A1, A2, A3, A4);
    if (sub < N_CAPS) {
      float acc = sel5(A0, A1, A2, A3, A4);
      int pair = g * N_CAPS + sub;
      sdot[pair] = acc;
      float num = acc - (float)D_CAPS * smm[pair] * meanq[sub];
      float den = sqrtf(sss[pair]) * sqrtf(ssq[sub]) + EPSF;
      pp[pair] = tanh_fast(num / den);
    }
  };

  auto mdot_aa = [&]() {
    float A0 = 0.f, A1 = 0.f, A2 = 0.f, A3 = 0.f, A4 = 0.f;
    DOT5(vv, A0, A1, A2, A3, A4);
    if (sub < N_CAPS) {
      float acc = sel5(A0, A1, A2, A3, A4);
      int pair = g * N_CAPS + sub;
      float mdv = sscale[sub] * acc;
      aa[pair] += pp[pair] * mdv;
      sdot[pair] = 0.5f * (sdot[pair] + mdv);
    }
  };

  auto p_from_S = [&]() {
    if (tid < NPAIR) {
      int c = tid - (tid / N_CAPS) * N_CAPS;
      float num = sdot[tid] - (float)D_CAPS * smm[tid] * meanq[c];
      float den = sqrtf(sss[tid]) * sqrtf(ssq[c]) + EPSF;
      pp[tid] = tanh_fast(num / den);
    }
  };

  auto softmax_dsp = [&]() {
    if (tid < I_CAPS) {
      float av[N_CAPS], ev[N_CAPS];
      float mx = -1e30f;
#pragma unroll
      for (int c = 0; c < N_CAPS; ++c) {
        av[c] = aa[tid * N_CAPS + c];
        mx = fmaxf(mx, av[c]);
      }
      float s = 0.f;
#pragma unroll
      for (int c = 0; c < N_CAPS; ++c) {
        ev[c] = __expf(av[c] - mx);
        s += ev[c];
      }
      float inv = 1.f / s;
#pragma unroll
      for (int c = 0; c < N_CAPS; ++c)
        dsp[tid * N_CAPS + c] = ev[c] * inv + pp[tid * N_CAPS + c];
    }
  };

  auto hat_v = [&]() {
    for (int cd = tid; cd < CD; cd += 1024) {
      int c = cd / D_CAPS, d = cd - c * D_CAPS;
      const float* col = hat_m + c * D_PAD + d;
      float b0 = 0.f, b1 = 0.f, b2 = 0.f, b3 = 0.f;
      float b4 = 0.f, b5 = 0.f, b6 = 0.f, b7 = 0.f;
#pragma unroll 4
      for (int i = 0; i < I_CAPS; i += 8) {
        b0 = fmaf(dsp[(i + 0) * N_CAPS + c], col[(i + 0) * MLD], b0);
        b1 = fmaf(dsp[(i + 1) * N_CAPS + c], col[(i + 1) * MLD], b1);
        b2 = fmaf(dsp[(i + 2) * N_CAPS + c], col[(i + 2) * MLD], b2);
        b3 = fmaf(dsp[(i + 3) * N_CAPS + c], col[(i + 3) * MLD], b3);
        b4 = fmaf(dsp[(i + 4) * N_CAPS + c], col[(i + 4) * MLD], b4);
        b5 = fmaf(dsp[(i + 5) * N_CAPS + c], col[(i + 5) * MLD], b5);
        b6 = fmaf(dsp[(i + 6) * N_CAPS + c], col[(i + 6) * MLD], b6);
        b7 = fmaf(dsp[(i + 7) * N_CAPS + c], col[(i + 7) * MLD], b7);
      }
      vv[c * D_PAD + d] = ((b0 + b1) + (b2 + b3)) + ((b4 + b5) + (b6 + b7));
    }
  };

  auto squash_scale = [&]() {
    if (w < N_CAPS) {
      const int c = w;
      float s2 = 0.f;
      for (int d = lane; d < D_CAPS; d += 64) {
        float x = vv[c * D_PAD + d];
        s2 = fmaf(x, x, s2);
      }
      s2 = wred(s2);
      if (lane == 0) sscale[c] = (s2 / (1.f + s2)) * rsqrtf(s2 + EPSF);
    }
  };

  qstats();
  __syncthreads();
  init_S_p();
  __syncthreads();

  for (int r = 0; r < 2; ++r) {
    softmax_dsp();
    __syncthreads();
    hat_v();
    __syncthreads();
    squash_scale();
    __syncthreads();
    mdot_aa();
    for (int cd = tid; cd < CD; cd += 1024) {
      int c = cd / D_CAPS, d = cd - c * D_CAPS;
      int l = c * D_PAD + d;
      tq[l] = 0.5f * (tq[l] + vv[l] * sscale[c]);
    }
    __syncthreads();
    qstats();
    __syncthreads();
    p_from_S();
    __syncthreads();
  }

  softmax_dsp();
  __syncthreads();
  hat_v();
  __syncthreads();
  squash_scale();
  __syncthreads();

  if (*flag == 0) {
    float* out = (float*)out_v;
    for (int cd = tid; cd < CD; cd += 1024) {
      int c = cd / D_CAPS, d = cd - c * D_CAPS;
      out[qi * CD + cd] = vv[c * D_PAD + d] * sscale[c];
    }
  } else {
    bf16* out = (bf16*)out_v;
    for (int cd = tid; cd < CD; cd += 1024) {
      int c = cd / D_CAPS, d = cd - c * D_CAPS;
      out[qi * CD + cd] = __float2bfloat16(vv[c * D_PAD + d] * sscale[c]);
    }
  }
  #undef DOT5
}

// ---------------------------------------------------------------------------
extern "C" void kernel_launch(void* const* d_in, const int* in_sizes, int n_in,
                              void* d_out, int out_size, void* d_ws, size_t ws_size,
                              hipStream_t stream) {
  // Bind inputs by element count (order-independent):
  // m=98304, q=196608, W=587520, b=765.
  const void *m = nullptr, *q = nullptr, *W = nullptr, *b = nullptr;
  for (int i = 0; i < n_in; ++i) {
    switch (in_sizes[i]) {
      case I_CAPS * IN_DIM: m = d_in[i]; break;
      case NQ * IN_DIM:     q = d_in[i]; break;
      case IN_DIM * CD:     W = d_in[i]; break;
      case CD:              b = d_in[i]; break;
      default: break;
    }
  }
  if (!m || !q || !W || !b) {
    m = d_in[0]; q = d_in[1]; W = d_in[2]; b = d_in[3];
  }

  int*   flag   = (int*)d_ws;
  float* mean_m = (float*)d_ws + 16;                 // 640
  float* ssm    = mean_m + 640;                      // 640
  float* hat_m  = ssm + 640;                         // 128 * 800 f32 (padded)
  float* hat_q  = hat_m + I_CAPS * MLD;              // 256 * 765 f32 (packed)

  classify_kernel<<<1, 64, 0, stream>>>((const unsigned*)m, flag);
  // zero hat_m (incl. pads) + hat_q in one contiguous memset (split-K atomics)
  hipMemsetAsync(hat_m, 0,
                 ((size_t)I_CAPS * MLD + (size_t)NQ * CD) * sizeof(float),
                 stream);
  gemm_kernel<<<dim3(12, 48, 2), dim3(64, 4), 0, stream>>>(m, q, W, b, flag,
                                                           hat_m, hat_q);
  stats_kernel<<<160, 256, 0, stream>>>(hat_m, mean_m, ssm);
  routing_kernel<<<NQ, 1024, 0, stream>>>(hat_m, hat_q, mean_m, ssm, flag,
                                          d_out);
}

// Round 11
// 121.110 us; speedup vs baseline: 1.6264x; 1.0565x over previous
//
#include <hip/hip_runtime.h>
#include <hip/hip_bf16.h>

// Problem constants (fixed by the reference)
#define I_CAPS 128
#define N_CAPS 5
#define D_CAPS 153
#define D_PAD  160      // padded capsule dim (16B-aligned c-blocks, zeros in 153..159)
#define MLD    800      // hat_m leading dim = 5 * 160
#define IN_DIM 768
#define NQ     256
#define CD     765      // N_CAPS * D_CAPS
#define NPAIR  640      // I_CAPS * N_CAPS
#define EPSF   1e-8f
#define KHALF  384      // IN_DIM / 2 (split-K)

typedef __hip_bfloat16 bf16;

__device__ __forceinline__ float wred(float x) {
#pragma unroll
  for (int off = 32; off; off >>= 1) x += __shfl_down(x, off, 64);
  return x;
}

// Stable fast tanh: sign(x) * (1 - e^{-2|x|}) / (1 + e^{-2|x|})
__device__ __forceinline__ float tanh_fast(float x) {
  float t = __expf(-2.f * fabsf(x));
  float r = (1.f - t) / (1.f + t);
  return copysignf(r, x);
}

// ---------------------------------------------------------------------------
// Kernel 0: input-dtype classifier (resolves to f32 here; kept for robustness)
// ---------------------------------------------------------------------------
__global__ void classify_kernel(const unsigned* __restrict__ m_u32,
                                int* __restrict__ flag) {
  int lane = threadIdx.x & 63;
  unsigned u = m_u32[lane];
  int e = (u >> 7) & 0xFF;
  int hit = (e >= 118 && e <= 134) ? 1 : 0;
  unsigned long long mask = __ballot(hit);
  if (lane == 0) *flag = (__popcll(mask) >= 48) ? 1 : 0;
}

// ---------------------------------------------------------------------------
// Kernel 1: GEMM — split-K x2, 8-row x 64-col tiles, atomicAdd combine.
// grid (12, 48, 2), block (64, 4). hat buffers pre-zeroed; kb==0 adds bias.
// ---------------------------------------------------------------------------
template <bool ISB>
__device__ __forceinline__ float ld_in(const void* p, long idx) {
  if (ISB) return __bfloat162float(((const bf16*)p)[idx]);
  return ((const float*)p)[idx];
}

template <bool ISB>
__device__ void gemm_body(const void* m, const void* q, const void* W,
                          const void* b, float* hat_m, float* hat_q) {
  __shared__ float As[8][KHALF];   // 12 KB
  const int tx = threadIdx.x, ty = threadIdx.y;
  const int t = ty * 64 + tx;      // 0..255
  const int row0 = blockIdx.y * 8;
  const int k0 = blockIdx.z * KHALF;

  if (ISB) {
    for (int e = t; e < 8 * KHALF; e += 256) {
      int rr = e / KHALF, kk = e - rr * KHALF;
      int row = row0 + rr;
      As[rr][kk] = (row < I_CAPS)
                       ? ld_in<true>(m, (long)row * IN_DIM + k0 + kk)
                       : ld_in<true>(q, (long)(row - I_CAPS) * IN_DIM + k0 + kk);
    }
  } else {
    for (int e = t; e < 8 * (KHALF / 4); e += 256) {
      int rr = e / (KHALF / 4), k4 = e - rr * (KHALF / 4);
      int row = row0 + rr;
      const float* src = (row < I_CAPS)
                             ? (const float*)m + (long)row * IN_DIM
                             : (const float*)q + (long)(row - I_CAPS) * IN_DIM;
      *(float4*)&As[rr][k4 * 4] = *(const float4*)(src + k0 + k4 * 4);
    }
  }
  __syncthreads();

  const int col = blockIdx.x * 64 + tx;
  const int colc = (col < CD) ? col : (CD - 1);
  const int r0 = ty * 2, r1 = r0 + 1;

  float a0a = 0.f, a0b = 0.f, a1a = 0.f, a1b = 0.f;
#pragma unroll 2
  for (int k = 0; k < KHALF; k += 8) {
    const float4 A0a = *(const float4*)&As[r0][k];
    const float4 A0b = *(const float4*)&As[r0][k + 4];
    const float4 A1a = *(const float4*)&As[r1][k];
    const float4 A1b = *(const float4*)&As[r1][k + 4];
    float w0 = ld_in<ISB>(W, (long)(k0 + k + 0) * CD + colc);
    float w1 = ld_in<ISB>(W, (long)(k0 + k + 1) * CD + colc);
    float w2 = ld_in<ISB>(W, (long)(k0 + k + 2) * CD + colc);
    float w3 = ld_in<ISB>(W, (long)(k0 + k + 3) * CD + colc);
    float w4 = ld_in<ISB>(W, (long)(k0 + k + 4) * CD + colc);
    float w5 = ld_in<ISB>(W, (long)(k0 + k + 5) * CD + colc);
    float w6 = ld_in<ISB>(W, (long)(k0 + k + 6) * CD + colc);
    float w7 = ld_in<ISB>(W, (long)(k0 + k + 7) * CD + colc);
    a0a = fmaf(A0a.x, w0, a0a); a0b = fmaf(A0a.y, w1, a0b);
    a0a = fmaf(A0a.z, w2, a0a); a0b = fmaf(A0a.w, w3, a0b);
    a0a = fmaf(A0b.x, w4, a0a); a0b = fmaf(A0b.y, w5, a0b);
    a0a = fmaf(A0b.z, w6, a0a); a0b = fmaf(A0b.w, w7, a0b);
    a1a = fmaf(A1a.x, w0, a1a); a1b = fmaf(A1a.y, w1, a1b);
    a1a = fmaf(A1a.z, w2, a1a); a1b = fmaf(A1a.w, w3, a1b);
    a1a = fmaf(A1b.x, w4, a1a); a1b = fmaf(A1b.y, w5, a1b);
    a1a = fmaf(A1b.z, w6, a1a); a1b = fmaf(A1b.w, w7, a1b);
  }

  if (col < CD) {
    float p0 = a0a + a0b;
    float p1 = a1a + a1b;
    if (blockIdx.z == 0) {
      float bias = ld_in<ISB>(b, col);
      p0 += bias;
      p1 += bias;
    }
    int c = col / D_CAPS, d = col - c * D_CAPS;
    int ra = row0 + r0, rb = row0 + r1;
    float* d0 = (ra < I_CAPS) ? &hat_m[ra * MLD + c * D_PAD + d]
                              : &hat_q[(ra - I_CAPS) * CD + col];
    float* d1 = (rb < I_CAPS) ? &hat_m[rb * MLD + c * D_PAD + d]
                              : &hat_q[(rb - I_CAPS) * CD + col];
    atomicAdd(d0, p0);
    atomicAdd(d1, p1);
  }
}

__global__ __launch_bounds__(256, 4)
void gemm_kernel(const void* m, const void* q, const void* W, const void* b,
                 const int* __restrict__ flag,
                 float* __restrict__ hat_m, float* __restrict__ hat_q) {
  if (*flag)
    gemm_body<true>(m, q, W, b, hat_m, hat_q);
  else
    gemm_body<false>(m, q, W, b, hat_m, hat_q);
}

// ---------------------------------------------------------------------------
// Kernel 2: per-(i,c) stats of hat_m — one wave per pair. grid 160, block 256.
// ---------------------------------------------------------------------------
__global__ __launch_bounds__(256)
void stats_kernel(const float* __restrict__ hat_m,
                  float* __restrict__ mean_m, float* __restrict__ ssm) {
  const int wave = threadIdx.x >> 6, lane = threadIdx.x & 63;
  const int pair = blockIdx.x * 4 + wave;
  const int i = pair / N_CAPS, c = pair - i * N_CAPS;
  const float* hm = hat_m + i * MLD + c * D_PAD;
  float s = 0.f, s2 = 0.f;
  for (int d = lane; d < D_CAPS; d += 64) {
    float x = hm[d];
    s += x;
    s2 = fmaf(x, x, s2);
  }
  s = wred(s);
  s2 = wred(s2);
  if (lane == 0) {
    float mu = s * (1.f / D_CAPS);
    mean_m[pair] = mu;
    ssm[pair] = fmaxf(s2 - (float)D_CAPS * mu * mu, 0.f);
  }
}

// ---------------------------------------------------------------------------
// Kernel 2b: Gram matrix G[c][j][i] = hm_i,c . hm_j,c (symmetric; both halves
// computed). grid (5, 128), block 128. Pads (d 153..159) are zero -> 40 x
// float4 dot is exact. 320 KB output, shared by all routing blocks via L2.
// ---------------------------------------------------------------------------
__global__ __launch_bounds__(128)
void gram_kernel(const float* __restrict__ hat_m, float* __restrict__ G) {
  const int c = blockIdx.x, j = blockIdx.y, i = threadIdx.x;
  const float4* hi = (const float4*)(hat_m + i * MLD + c * D_PAD);
  const float4* hj = (const float4*)(hat_m + j * MLD + c * D_PAD);
  float a0 = 0.f, a1 = 0.f, a2 = 0.f, a3 = 0.f;
#pragma unroll 8
  for (int k = 0; k < 40; ++k) {
    float4 x = hi[k];
    float4 y = hj[k];
    a0 = fmaf(x.x, y.x, a0);
    a1 = fmaf(x.y, y.y, a1);
    a2 = fmaf(x.z, y.z, a2);
    a3 = fmaf(x.w, y.w, a3);
  }
  G[c * 16384 + j * 128 + i] = (a0 + a1) + (a2 + a3);
}

// ---------------------------------------------------------------------------
// Kernel 3: routing — one block per query, 1024 threads.
// Gram-assisted rounds: hm.v = (G.dsp)_i, |vv|^2 = dsp^T G dsp,
// sum(tq.vv) = sum_i dsp_i S_i, sum(vv) = sum_i dsp_i D mean_m -> rounds
// touch NO hat_m. hat_m passes: init S (DOT5) + final hat_v only.
// ---------------------------------------------------------------------------
__global__ __launch_bounds__(1024, 4)
void routing_kernel(const float* __restrict__ hat_m,
                    const float* __restrict__ hat_q,
                    const float* __restrict__ Gmat,
                    const float* __restrict__ mean_m,
                    const float* __restrict__ ssm,
                    const int* __restrict__ flag,
                    void* __restrict__ out_v) {
  __shared__ float tq[N_CAPS * D_PAD], vv[N_CAPS * D_PAD];
  __shared__ float aa[NPAIR], pp[NPAIR], dsp[NPAIR], sdot[NPAIR];
  __shared__ float smm[NPAIR], sss[NPAIR];
  __shared__ float meanq[N_CAPS], ssq[N_CAPS], sc_s[N_CAPS];
  __shared__ float tsum_s[N_CAPS], t2_s[N_CAPS];
  __shared__ float red[10][4];   // per-wave partials: n2, vsum, sdotd

  const int tid = threadIdx.x;
  const int qi = blockIdx.x;
  const int w = tid >> 6, lane = tid & 63;
  const int g = tid >> 3, sub = tid & 7;   // 128 groups of 8 lanes; i = g
  const float* hq = hat_q + qi * CD;
  const float* hm = hat_m + g * MLD;

  for (int l = tid; l < N_CAPS * D_PAD; l += 1024) {
    int c = l / D_PAD, d = l - c * D_PAD;
    tq[l] = (d < D_CAPS) ? hq[c * D_CAPS + d] : 0.f;
  }
  if (tid < NPAIR) {
    aa[tid] = 0.f;
    smm[tid] = mean_m[tid];
    sss[tid] = ssm[tid];
  }
  __syncthreads();

  // initial per-c stats of tq; also save raw Tsum, T2 for the recurrence
  if (w < N_CAPS) {
    const int c = w;
    float s = 0.f, s2 = 0.f;
    for (int d = lane; d < D_CAPS; d += 64) {
      float x = tq[c * D_PAD + d];
      s += x;
      s2 = fmaf(x, x, s2);
    }
    s = wred(s);
    s2 = wred(s2);
    if (lane == 0) {
      float mu = s * (1.f / D_CAPS);
      tsum_s[c] = s;
      t2_s[c] = s2;
      meanq[c] = mu;
      ssq[c] = fmaxf(s2 - (float)D_CAPS * mu * mu, 0.f);
    }
  }
  __syncthreads();

  // init S = hm.tq (the only tq DOT; 8-lane group per i, 5 c-chains)
  {
    float A0 = 0.f, A1 = 0.f, A2 = 0.f, A3 = 0.f, A4 = 0.f;
#pragma unroll 2
    for (int jj = 0; jj < 5; ++jj) {
      int d = jj * 32 + sub * 4;
      float4 h0 = *(const float4*)(hm + 0 * D_PAD + d);
      float4 h1 = *(const float4*)(hm + 1 * D_PAD + d);
      float4 h2 = *(const float4*)(hm + 2 * D_PAD + d);
      float4 h3 = *(const float4*)(hm + 3 * D_PAD + d);
      float4 h4 = *(const float4*)(hm + 4 * D_PAD + d);
      float4 t0 = *(const float4*)(tq + 0 * D_PAD + d);
      float4 t1 = *(const float4*)(tq + 1 * D_PAD + d);
      float4 t2 = *(const float4*)(tq + 2 * D_PAD + d);
      float4 t3 = *(const float4*)(tq + 3 * D_PAD + d);
      float4 t4 = *(const float4*)(tq + 4 * D_PAD + d);
      A0 = fmaf(h0.x, t0.x, A0); A0 = fmaf(h0.y, t0.y, A0);
      A0 = fmaf(h0.z, t0.z, A0); A0 = fmaf(h0.w, t0.w, A0);
      A1 = fmaf(h1.x, t1.x, A1); A1 = fmaf(h1.y, t1.y, A1);
      A1 = fmaf(h1.z, t1.z, A1); A1 = fmaf(h1.w, t1.w, A1);
      A2 = fmaf(h2.x, t2.x, A2); A2 = fmaf(h2.y, t2.y, A2);
      A2 = fmaf(h2.z, t2.z, A2); A2 = fmaf(h2.w, t2.w, A2);
      A3 = fmaf(h3.x, t3.x, A3); A3 = fmaf(h3.y, t3.y, A3);
      A3 = fmaf(h3.z, t3.z, A3); A3 = fmaf(h3.w, t3.w, A3);
      A4 = fmaf(h4.x, t4.x, A4); A4 = fmaf(h4.y, t4.y, A4);
      A4 = fmaf(h4.z, t4.z, A4); A4 = fmaf(h4.w, t4.w, A4);
    }
#pragma unroll
    for (int off = 1; off < 8; off <<= 1) {
      A0 += __shfl_xor(A0, off, 64);
      A1 += __shfl_xor(A1, off, 64);
      A2 += __shfl_xor(A2, off, 64);
      A3 += __shfl_xor(A3, off, 64);
      A4 += __shfl_xor(A4, off, 64);
    }
    if (sub < N_CAPS) {
      float acc = A0;
      acc = (sub == 1) ? A1 : acc;
      acc = (sub == 2) ? A2 : acc;
      acc = (sub == 3) ? A3 : acc;
      acc = (sub == 4) ? A4 : acc;
      int ic = g * N_CAPS + sub;
      sdot[ic] = acc;
      float num = acc - (float)D_CAPS * smm[ic] * meanq[sub];
      float den = sqrtf(sss[ic]) * sqrtf(ssq[sub]) + EPSF;
      pp[ic] = tanh_fast(num / den);
    }
  }
  __syncthreads();

  auto softmax_dsp = [&]() {
    if (tid < I_CAPS) {
      float av[N_CAPS], ev[N_CAPS];
      float mx = -1e30f;
#pragma unroll
      for (int c = 0; c < N_CAPS; ++c) {
        av[c] = aa[tid * N_CAPS + c];
        mx = fmaxf(mx, av[c]);
      }
      float s = 0.f;
#pragma unroll
      for (int c = 0; c < N_CAPS; ++c) {
        ev[c] = __expf(av[c] - mx);
        s += ev[c];
      }
      float inv = 1.f / s;
#pragma unroll
      for (int c = 0; c < N_CAPS; ++c)
        dsp[tid * N_CAPS + c] = ev[c] * inv + pp[tid * N_CAPS + c];
    }
  };

  // ---- Gram-assisted rounds: no hat_m traffic ----
  for (int r = 0; r < 2; ++r) {
    softmax_dsp();
    __syncthreads();
    float y = 0.f, sold = 0.f;
    int cc = 0, ii = 0, ic = 0;
    if (tid < NPAIR) {
      cc = tid >> 7;              // 128 consecutive threads per c
      ii = tid & 127;
      ic = ii * N_CAPS + cc;
      const float* Gp = Gmat + cc * 16384 + ii;
      float y0 = 0.f, y1 = 0.f;
#pragma unroll 4
      for (int j = 0; j < 128; j += 2) {
        y0 = fmaf(Gp[j * 128], dsp[j * N_CAPS + cc], y0);
        y1 = fmaf(Gp[(j + 1) * 128], dsp[(j + 1) * N_CAPS + cc], y1);
      }
      y = y0 + y1;                // = hm_i . vv_raw
      sold = sdot[ic];
      float dmy = dsp[ic];
      float n2p = dmy * y;
      float vsp = dmy * ((float)D_CAPS * smm[ic]);
      float sdp = dmy * sold;
      n2p = wred(n2p);
      vsp = wred(vsp);
      sdp = wred(sdp);
      if (lane == 0) {
        red[w][0] = n2p;
        red[w][1] = vsp;
        red[w][2] = sdp;
      }
    }
    __syncthreads();
    if (tid < N_CAPS) {
      float n2 = red[2 * tid][0] + red[2 * tid + 1][0];
      float vs = red[2 * tid][1] + red[2 * tid + 1][1];
      float sd = red[2 * tid][2] + red[2 * tid + 1][2];
      float sc = (n2 / (1.f + n2)) * rsqrtf(n2 + EPSF);
      sc_s[tid] = sc;
      float ts = 0.5f * (tsum_s[tid] + sc * vs);
      float t2 = 0.25f * (t2_s[tid] + 2.f * sc * sd + sc * sc * n2);
      tsum_s[tid] = ts;
      t2_s[tid] = t2;
      float mu = ts * (1.f / D_CAPS);
      meanq[tid] = mu;
      ssq[tid] = fmaxf(t2 - (float)D_CAPS * mu * mu, 0.f);
    }
    __syncthreads();
    if (tid < NPAIR) {
      float mdv = sc_s[cc] * y;          // hm_i . v
      aa[ic] += pp[ic] * mdv;
      float snew = 0.5f * (sold + mdv);  // S' = 0.5(S + hm.v)
      sdot[ic] = snew;
      float num = snew - (float)D_CAPS * smm[ic] * meanq[cc];
      float den = sqrtf(sss[ic]) * sqrtf(ssq[cc]) + EPSF;
      pp[ic] = tanh_fast(num / den);
    }
    __syncthreads();
  }

  // ---- final: d+p -> hat_v (one hat_m pass) -> squash -> out ----
  softmax_dsp();
  __syncthreads();
  for (int cd = tid; cd < CD; cd += 1024) {
    int c = cd / D_CAPS, d = cd - c * D_CAPS;
    const float* col = hat_m + c * D_PAD + d;
    float b0 = 0.f, b1 = 0.f, b2 = 0.f, b3 = 0.f;
    float b4 = 0.f, b5 = 0.f, b6 = 0.f, b7 = 0.f;
#pragma unroll 4
    for (int i = 0; i < I_CAPS; i += 8) {
      b0 = fmaf(dsp[(i + 0) * N_CAPS + c], col[(i + 0) * MLD], b0);
      b1 = fmaf(dsp[(i + 1) * N_CAPS + c], col[(i + 1) * MLD], b1);
      b2 = fmaf(dsp[(i + 2) * N_CAPS + c], col[(i + 2) * MLD], b2);
      b3 = fmaf(dsp[(i + 3) * N_CAPS + c], col[(i + 3) * MLD], b3);
      b4 = fmaf(dsp[(i + 4) * N_CAPS + c], col[(i + 4) * MLD], b4);
      b5 = fmaf(dsp[(i + 5) * N_CAPS + c], col[(i + 5) * MLD], b5);
      b6 = fmaf(dsp[(i + 6) * N_CAPS + c], col[(i + 6) * MLD], b6);
      b7 = fmaf(dsp[(i + 7) * N_CAPS + c], col[(i + 7) * MLD], b7);
    }
    vv[c * D_PAD + d] = ((b0 + b1) + (b2 + b3)) + ((b4 + b5) + (b6 + b7));
  }
  __syncthreads();
  if (w < N_CAPS) {
    const int c = w;
    float s2 = 0.f;
    for (int d = lane; d < D_CAPS; d += 64) {
      float x = vv[c * D_PAD + d];
      s2 = fmaf(x, x, s2);
    }
    s2 = wred(s2);
    if (lane == 0) sc_s[c] = (s2 / (1.f + s2)) * rsqrtf(s2 + EPSF);
  }
  __syncthreads();

  if (*flag == 0) {
    float* out = (float*)out_v;
    for (int cd = tid; cd < CD; cd += 1024) {
      int c = cd / D_CAPS, d = cd - c * D_CAPS;
      out[qi * CD + cd] = vv[c * D_PAD + d] * sc_s[c];
    }
  } else {
    bf16* out = (bf16*)out_v;
    for (int cd = tid; cd < CD; cd += 1024) {
      int c = cd / D_CAPS, d = cd - c * D_CAPS;
      out[qi * CD + cd] = __float2bfloat16(vv[c * D_PAD + d] * sc_s[c]);
    }
  }
}

// ---------------------------------------------------------------------------
extern "C" void kernel_launch(void* const* d_in, const int* in_sizes, int n_in,
                              void* d_out, int out_size, void* d_ws, size_t ws_size,
                              hipStream_t stream) {
  // Bind inputs by element count (order-independent):
  // m=98304, q=196608, W=587520, b=765.
  const void *m = nullptr, *q = nullptr, *W = nullptr, *b = nullptr;
  for (int i = 0; i < n_in; ++i) {
    switch (in_sizes[i]) {
      case I_CAPS * IN_DIM: m = d_in[i]; break;
      case NQ * IN_DIM:     q = d_in[i]; break;
      case IN_DIM * CD:     W = d_in[i]; break;
      case CD:              b = d_in[i]; break;
      default: break;
    }
  }
  if (!m || !q || !W || !b) {
    m = d_in[0]; q = d_in[1]; W = d_in[2]; b = d_in[3];
  }

  int*   flag   = (int*)d_ws;
  float* mean_m = (float*)d_ws + 16;                 // 640
  float* ssm    = mean_m + 640;                      // 640
  float* hat_m  = ssm + 640;                         // 128 * 800 (padded)
  float* hat_q  = hat_m + I_CAPS * MLD;              // 256 * 765 (packed)
  float* G      = hat_q + NQ * CD;                   // 5 * 128 * 128

  classify_kernel<<<1, 64, 0, stream>>>((const unsigned*)m, flag);
  // zero hat_m (incl. pads) + hat_q (split-K atomics accumulate into these)
  hipMemsetAsync(hat_m, 0,
                 ((size_t)I_CAPS * MLD + (size_t)NQ * CD) * sizeof(float),
                 stream);
  gemm_kernel<<<dim3(12, 48, 2), dim3(64, 4), 0, stream>>>(m, q, W, b, flag,
                                                           hat_m, hat_q);
  stats_kernel<<<160, 256, 0, stream>>>(hat_m, mean_m, ssm);
  gram_kernel<<<dim3(N_CAPS, I_CAPS), 128, 0, stream>>>(hat_m, G);
  routing_kernel<<<NQ, 1024, 0, stream>>>(hat_m, hat_q, G, mean_m, ssm, flag,
                                          d_out);
}